// Round 2
// baseline (444.777 us; speedup 1.0000x reference)
//
#include <hip/hip_runtime.h>

// MoE top-1 layer, MI355X. N=8192 tokens, D=1024, F=4096, E=8.
// R5: gemm -> 256x256 tile, 8 waves (512 thr), BK=64, double-buffered LDS
//   (128 KB, 1 block/CU), minimum-2-phase schedule per T3 recipe:
//   STAGE(buf^1, t+1) at top -> compute buf -> vmcnt(0) -> ONE barrier.
//   Loads in flight across the whole 64-MFMA compute phase (~640 cyc/SIMD
//   > LLC latency). Reference: m248 grouped-GEMM 256^2 K=1024 2ph = 655 TF.
// prep/route unchanged except route tile granularity BM=256.

#define N_TOKENS 8192
#define D_MODEL  1024
#define D_FF     4096
#define N_EXPERTS 8

#define BM 256
#define BN 256
#define BK 64
#define NKT (D_MODEL / BK)                   // 16 k-iterations
#define MT_MAX (N_TOKENS / BM + N_EXPERTS)   // 40 m-tiles worst case
#define NTILES (D_FF / BN)                   // 16 n-tiles
#define GATE_BLOCKS (N_TOKENS / 4)           // 2048
#define WCONV_BLOCKS ((D_FF / 64) * (D_MODEL / 64) * N_EXPERTS)  // 8192

typedef float  floatx4 __attribute__((ext_vector_type(4)));
typedef short  short8  __attribute__((ext_vector_type(8)));

__device__ __forceinline__ unsigned short f2bf(float f) {
    union { float f; unsigned u; } a; a.f = f;
    return (unsigned short)((a.u + 0x7fffu + ((a.u >> 16) & 1u)) >> 16); // RNE
}

#define GLDS(gp, lp) __builtin_amdgcn_global_load_lds( \
    (const __attribute__((address_space(1))) unsigned int*)(const void*)(gp), \
    (__attribute__((address_space(3))) unsigned int*)(void*)(lp), 16, 0, 0)

// -------- prep: gate (fp32, writes top1 + xb) ∪ wconv (ew -> wt bf16 [E][F][D]) --------
#define WST 68
__global__ __launch_bounds__(256) void prep_kernel(
    const float* __restrict__ x, const float* __restrict__ gw,
    const float* __restrict__ gb, const float* __restrict__ ew,
    unsigned short* __restrict__ xb, unsigned short* __restrict__ wt,
    int* __restrict__ top1)
{
    if (blockIdx.x < GATE_BLOCKS) {
        int wave = threadIdx.x >> 6;
        int l    = threadIdx.x & 63;
        int n = blockIdx.x * 4 + wave;
        const float4* xr = (const float4*)(x + (size_t)n * D_MODEL);
        float acc[N_EXPERTS];
#pragma unroll
        for (int e = 0; e < N_EXPERTS; ++e) acc[e] = 0.f;
#pragma unroll
        for (int j = 0; j < 4; ++j) {
            int d4 = j * 64 + l;
            float4 v = xr[d4];
            float vv[4] = { v.x, v.y, v.z, v.w };
#pragma unroll
            for (int t = 0; t < 4; ++t) {
                const float4* g = (const float4*)(gw + (size_t)(d4 * 4 + t) * N_EXPERTS);
                float4 g0 = g[0], g1 = g[1];
                acc[0] += vv[t] * g0.x; acc[1] += vv[t] * g0.y;
                acc[2] += vv[t] * g0.z; acc[3] += vv[t] * g0.w;
                acc[4] += vv[t] * g1.x; acc[5] += vv[t] * g1.y;
                acc[6] += vv[t] * g1.z; acc[7] += vv[t] * g1.w;
            }
            union { unsigned short us[4]; uint2 u; } pk;
            pk.us[0] = f2bf(v.x); pk.us[1] = f2bf(v.y);
            pk.us[2] = f2bf(v.z); pk.us[3] = f2bf(v.w);
            ((uint2*)(xb + (size_t)n * D_MODEL))[d4] = pk.u;
        }
#pragma unroll
        for (int e = 0; e < N_EXPERTS; ++e)
            for (int off = 32; off > 0; off >>= 1)
                acc[e] += __shfl_down(acc[e], off);
        if (l == 0) {
            float best = acc[0] + gb[0]; int be = 0;
#pragma unroll
            for (int e = 1; e < N_EXPERTS; ++e) {
                float v = acc[e] + gb[e];
                if (v > best) { best = v; be = e; }
            }
            top1[n] = be;
        }
    } else {
        __shared__ unsigned short tt[64 * WST];
        int b  = blockIdx.x - GATE_BLOCKS;
        int f0 = (b & 63) * 64;
        int d0 = ((b >> 6) & 15) * 64;
        int e  = b >> 10;
        int t  = threadIdx.x;
        const float* we = ew + (size_t)e * D_MODEL * D_FF + (size_t)d0 * D_FF + f0;
        int fg = (t & 15) * 4;
        int dg = (t >> 4) * 4;
        unsigned short v[4][4];
#pragma unroll
        for (int j = 0; j < 4; ++j) {
            float4 r = *(const float4*)(we + (size_t)(dg + j) * D_FF + fg);
            v[0][j] = f2bf(r.x); v[1][j] = f2bf(r.y);
            v[2][j] = f2bf(r.z); v[3][j] = f2bf(r.w);
        }
#pragma unroll
        for (int i = 0; i < 4; ++i) {
            union { unsigned short us[4]; uint2 u; } pk;
            pk.us[0] = v[i][0]; pk.us[1] = v[i][1];
            pk.us[2] = v[i][2]; pk.us[3] = v[i][3];
            *(uint2*)&tt[(fg + i) * WST + dg] = pk.u;
        }
        __syncthreads();
        unsigned short* wte = wt + (size_t)e * D_FF * D_MODEL + (size_t)f0 * D_MODEL + d0;
        int fr = t >> 3;
        int dr = (t & 7) * 8;
#pragma unroll
        for (int p = 0; p < 2; ++p) {
            int f = fr + p * 32;
            uint2 a = *(const uint2*)&tt[f * WST + dr];
            uint2 c = *(const uint2*)&tt[f * WST + dr + 4];
            uint4 o; o.x = a.x; o.y = a.y; o.z = c.x; o.w = c.y;
            *(uint4*)(wte + (size_t)f * D_MODEL + dr) = o;
        }
    }
}

// -------- route: single block, histogram + scan + order-preserving scatter --------
__global__ __launch_bounds__(1024) void route_kernel(
    const int* __restrict__ top1, int* __restrict__ tile_expert, int* __restrict__ list)
{
    __shared__ int wtot[16][N_EXPERTS];
    __shared__ int wbase[16][N_EXPERTS];
    __shared__ int pofs[N_EXPERTS];
    int t = threadIdx.x, wv = t >> 6, l = t & 63;

    for (int i = t; i < MT_MAX * BM; i += 1024) list[i] = -1;

    int e8[8];
    const int4* tp = (const int4*)(top1 + t * 8);
    int4 a = tp[0], b = tp[1];
    e8[0] = a.x; e8[1] = a.y; e8[2] = a.z; e8[3] = a.w;
    e8[4] = b.x; e8[5] = b.y; e8[6] = b.z; e8[7] = b.w;
    int c[N_EXPERTS], s[N_EXPERTS];
#pragma unroll
    for (int e = 0; e < N_EXPERTS; ++e) c[e] = 0;
#pragma unroll
    for (int j = 0; j < 8; ++j) c[e8[j]]++;
#pragma unroll
    for (int e = 0; e < N_EXPERTS; ++e) s[e] = c[e];
    for (int off = 1; off < 64; off <<= 1) {
#pragma unroll
        for (int e = 0; e < N_EXPERTS; ++e) {
            int v = __shfl_up(s[e], off);
            if (l >= off) s[e] += v;
        }
    }
    if (l == 63)
#pragma unroll
        for (int e = 0; e < N_EXPERTS; ++e) wtot[wv][e] = s[e];
    __syncthreads();
    if (t == 0) {
        int cnt[N_EXPERTS];
        for (int e = 0; e < N_EXPERTS; ++e) {
            cnt[e] = 0;
            for (int w = 0; w < 16; ++w) { wbase[w][e] = cnt[e]; cnt[e] += wtot[w][e]; }
        }
        int off = 0;
        for (int e = 0; e < N_EXPERTS; ++e) {
            pofs[e] = off;
            int ntl = (cnt[e] + BM - 1) / BM;
            for (int k = 0; k < ntl; ++k) tile_expert[off / BM + k] = e;
            off += ntl * BM;
        }
        for (int k = off / BM; k < MT_MAX; ++k) tile_expert[k] = -1;
    }
    __syncthreads();
    int base[N_EXPERTS];
#pragma unroll
    for (int e = 0; e < N_EXPERTS; ++e) base[e] = pofs[e] + wbase[wv][e] + s[e] - c[e];
#pragma unroll
    for (int j = 0; j < 8; ++j) {
        int e = e8[j];
        list[base[e]++] = t * 8 + j;
    }
}

// -------- grouped GEMM: 256x256, 8 waves, BK=64, 2-phase 1-barrier pipeline --------
__global__ __launch_bounds__(512, 2) void gemm_kernel(
    const unsigned short* __restrict__ xb,   // [N][D] bf16
    const unsigned short* __restrict__ wt,   // [E][F][D] bf16
    const float* __restrict__ eb,            // [E][F]
    const int* __restrict__ tile_expert,
    const int* __restrict__ list,
    float* __restrict__ out)                 // [N][F]
{
    int bid = blockIdx.x;
    int xcd = bid & 7, w = bid >> 3;         // w 0..79
    int mt  = w >> 1;                        // 0..39
    int nt  = (xcd << 1) | (w & 1);          // each XCD owns 2 n-columns
    int e = tile_expert[mt];
    if (e < 0) return;
    int n0 = nt * BN;

    __shared__ unsigned short As[2][BM * BK];   // 2 x 32 KB
    __shared__ unsigned short Bs[2][BN * BK];   // 2 x 32 KB
    __shared__ int toks[BM];

    int tid = threadIdx.x;
    int lane = tid & 63, wave = tid >> 6;       // wave 0..7
    if (tid < BM) toks[tid] = list[mt * BM + tid];
    __syncthreads();

    // staging: 2048 16B-chunks per operand per K-tile; 4 GLDS/wave each.
    // LDS slot s holds logical chunk (row = s>>3, c8 = (s&7) ^ (row&7)).
    const unsigned short* gA[4];
    const unsigned short* gB[4];
    const unsigned short* wbp = wt + (size_t)e * D_FF * D_MODEL;
#pragma unroll
    for (int i = 0; i < 4; ++i) {
        int s = wave * 256 + i * 64 + lane;     // 0..2047
        int row = s >> 3, c8 = (s & 7) ^ (row & 7);
        int ta = toks[row]; if (ta < 0) ta = 0;
        gA[i] = xb + (size_t)ta * D_MODEL + c8 * 8;
        gB[i] = wbp + (size_t)(n0 + row) * D_MODEL + c8 * 8;
    }

    // 8 GLDS instructions per wave per K-tile (4 A + 4 B).
    auto stage = [&](int b, int kt) {
        int k0 = kt * BK;
        unsigned short* ap = &As[b][0];
        unsigned short* bp = &Bs[b][0];
#pragma unroll
        for (int i = 0; i < 4; ++i) GLDS(gA[i] + k0, ap + (size_t)(wave * 256 + i * 64) * 8);
#pragma unroll
        for (int i = 0; i < 4; ++i) GLDS(gB[i] + k0, bp + (size_t)(wave * 256 + i * 64) * 8);
    };

    floatx4 acc[8][4];
#pragma unroll
    for (int mi = 0; mi < 8; ++mi)
#pragma unroll
        for (int ni = 0; ni < 4; ++ni)
            acc[mi][ni] = (floatx4){0.f, 0.f, 0.f, 0.f};

    int wr = wave >> 2, wc = wave & 3;
    int mw = wr * 128, nw = wc * 64;            // per-wave output origin
    int q = lane >> 4, r = lane & 15;
    int xr = r & 7;
    int ra[8], rb[4];
#pragma unroll
    for (int i = 0; i < 8; ++i) ra[i] = (mw + i * 16 + r) * 8;
#pragma unroll
    for (int i = 0; i < 4; ++i) rb[i] = (nw + i * 16 + r) * 8;

    // prologue: tile 0 into buf0, drain, barrier.
    stage(0, 0);
    asm volatile("s_waitcnt vmcnt(0)" ::: "memory");
    __builtin_amdgcn_s_barrier();
    __builtin_amdgcn_sched_barrier(0);

    for (int kt = 0; kt < NKT; ++kt) {
        int cur = kt & 1;
        if (kt + 1 < NKT) stage(cur ^ 1, kt + 1);   // loads fly under compute
        const unsigned short* Ac = &As[cur][0];
        const unsigned short* Bc = &Bs[cur][0];
#pragma unroll
        for (int ks = 0; ks < 2; ++ks) {
            int cq = (ks * 4 + q) ^ xr;
            short8 af[8], bf[4];
#pragma unroll
            for (int mi = 0; mi < 8; ++mi)
                af[mi] = *(const short8*)&Ac[(size_t)(ra[mi] + cq) * 8];
#pragma unroll
            for (int ni = 0; ni < 4; ++ni)
                bf[ni] = *(const short8*)&Bc[(size_t)(rb[ni] + cq) * 8];
#pragma unroll
            for (int mi = 0; mi < 8; ++mi)
#pragma unroll
                for (int ni = 0; ni < 4; ++ni)
                    acc[mi][ni] = __builtin_amdgcn_mfma_f32_16x16x32_bf16(
                        af[mi], bf[ni], acc[mi][ni], 0, 0, 0);
        }
        __builtin_amdgcn_sched_barrier(0);
        asm volatile("s_waitcnt vmcnt(0)" ::: "memory"); // own stage landed
        __builtin_amdgcn_s_barrier();                    // all staged + all reads done
        __builtin_amdgcn_sched_barrier(0);
    }

    // epilogue: C/D layout col=lane&15, row=(lane>>4)*4+i  [m89-verified]
#pragma unroll
    for (int ni = 0; ni < 4; ++ni) {
        int f = n0 + nw + ni * 16 + r;
        float bias = eb[(size_t)e * D_FF + f];
#pragma unroll
        for (int mi = 0; mi < 8; ++mi) {
            int mbase = mw + mi * 16 + q * 4;
#pragma unroll
            for (int i = 0; i < 4; ++i) {
                int tok = toks[mbase + i];
                if (tok >= 0) out[(size_t)tok * D_FF + f] = acc[mi][ni][i] + bias;
            }
        }
    }
}

extern "C" void kernel_launch(void* const* d_in, const int* in_sizes, int n_in,
                              void* d_out, int out_size, void* d_ws, size_t ws_size,
                              hipStream_t stream) {
    const float* x  = (const float*)d_in[0];
    const float* gw = (const float*)d_in[1];
    const float* gb = (const float*)d_in[2];
    const float* ew = (const float*)d_in[3];
    const float* eb = (const float*)d_in[4];
    float* out = (float*)d_out;

    char* ws = (char*)d_ws;
    int* top1        = (int*)ws;                    // 32 KB
    int* tile_expert = (int*)(ws + 32768);          // 160 B
    int* list        = (int*)(ws + 36864);          // 40*256*4 = 40960 B
    unsigned short* xb = (unsigned short*)(ws + 131072);                          // 16.8 MB
    unsigned short* wt = (unsigned short*)(ws + 131072 + (size_t)N_TOKENS * D_MODEL * 2); // 67 MB

    hipLaunchKernelGGL(prep_kernel, dim3(GATE_BLOCKS + WCONV_BLOCKS), dim3(256), 0, stream,
                       x, gw, gb, ew, xb, wt, top1);
    hipLaunchKernelGGL(route_kernel, dim3(1), dim3(1024), 0, stream,
                       top1, tile_expert, list);
    hipLaunchKernelGGL(gemm_kernel, dim3(MT_MAX * NTILES), dim3(512), 0, stream,
                       xb, wt, eb, tile_expert, list, out);
}

// Round 3
// 440.685 us; speedup vs baseline: 1.0093x; 1.0093x over previous
//
#include <hip/hip_runtime.h>

// MoE top-1 layer, MI355X. N=8192 tokens, D=1024, F=4096, E=8.
// R6: (a) gemm reverted to R4 exact (best measured 161.4 us: 128^2 tile,
//     BK=64 double-buffer, stage-ahead-2 with counted vmcnt(8), XOR-swizzle).
//     (b) prep SPLIT into gate_kernel + wconv_kernel for per-kernel rocprof
//     visibility of the ~270 us non-gemm time. (c) wconv retiled to
//     64f x 256d so global writes are 512B-contiguous per wt row.

#define N_TOKENS 8192
#define D_MODEL  1024
#define D_FF     4096
#define N_EXPERTS 8

#define BM 128
#define BN 128
#define BK 64
#define NKT (D_MODEL / BK)                   // 16 k-iterations
#define MT_MAX (N_TOKENS / BM + N_EXPERTS)   // 72 m-tiles worst case
#define NTILES (D_FF / BN)                   // 32 n-tiles
#define GATE_BLOCKS (N_TOKENS / 4)           // 2048
#define WCONV_BLOCKS ((D_FF / 64) * (D_MODEL / 256) * N_EXPERTS)  // 2048

typedef float  floatx4 __attribute__((ext_vector_type(4)));
typedef short  short8  __attribute__((ext_vector_type(8)));

__device__ __forceinline__ unsigned short f2bf(float f) {
    union { float f; unsigned u; } a; a.f = f;
    return (unsigned short)((a.u + 0x7fffu + ((a.u >> 16) & 1u)) >> 16); // RNE
}

#define GLDS(gp, lp) __builtin_amdgcn_global_load_lds( \
    (const __attribute__((address_space(1))) unsigned int*)(const void*)(gp), \
    (__attribute__((address_space(3))) unsigned int*)(void*)(lp), 16, 0, 0)

// -------- gate: fp32 gemv -> top1, + x -> xb bf16 --------
__global__ __launch_bounds__(256) void gate_kernel(
    const float* __restrict__ x, const float* __restrict__ gw,
    const float* __restrict__ gb,
    unsigned short* __restrict__ xb, int* __restrict__ top1)
{
    int wave = threadIdx.x >> 6;
    int l    = threadIdx.x & 63;
    int n = blockIdx.x * 4 + wave;
    const float4* xr = (const float4*)(x + (size_t)n * D_MODEL);
    float acc[N_EXPERTS];
#pragma unroll
    for (int e = 0; e < N_EXPERTS; ++e) acc[e] = 0.f;
#pragma unroll
    for (int j = 0; j < 4; ++j) {
        int d4 = j * 64 + l;
        float4 v = xr[d4];
        float vv[4] = { v.x, v.y, v.z, v.w };
#pragma unroll
        for (int t = 0; t < 4; ++t) {
            const float4* g = (const float4*)(gw + (size_t)(d4 * 4 + t) * N_EXPERTS);
            float4 g0 = g[0], g1 = g[1];
            acc[0] += vv[t] * g0.x; acc[1] += vv[t] * g0.y;
            acc[2] += vv[t] * g0.z; acc[3] += vv[t] * g0.w;
            acc[4] += vv[t] * g1.x; acc[5] += vv[t] * g1.y;
            acc[6] += vv[t] * g1.z; acc[7] += vv[t] * g1.w;
        }
        union { unsigned short us[4]; uint2 u; } pk;
        pk.us[0] = f2bf(v.x); pk.us[1] = f2bf(v.y);
        pk.us[2] = f2bf(v.z); pk.us[3] = f2bf(v.w);
        ((uint2*)(xb + (size_t)n * D_MODEL))[d4] = pk.u;
    }
#pragma unroll
    for (int e = 0; e < N_EXPERTS; ++e)
        for (int off = 32; off > 0; off >>= 1)
            acc[e] += __shfl_down(acc[e], off);
    if (l == 0) {
        float best = acc[0] + gb[0]; int be = 0;
#pragma unroll
        for (int e = 1; e < N_EXPERTS; ++e) {
            float v = acc[e] + gb[e];
            if (v > best) { best = v; be = e; }
        }
        top1[n] = be;
    }
}

// -------- wconv: ew f32 [E][D][F] -> wt bf16 [E][F][D], 64f x 256d tiles --------
// Read: 256B segments per d-row (as before). Write: 512B contiguous per f-row
// (4x the old 128B segments). LDS transpose with uint2-packed writes.
#define WST2 260
__global__ __launch_bounds__(256) void wconv_kernel(
    const float* __restrict__ ew, unsigned short* __restrict__ wt)
{
    __shared__ unsigned short tt[64 * WST2];   // 33.3 KB
    int b  = blockIdx.x;
    int f0 = (b & 63) * 64;                    // 64 f-tiles
    int d0 = ((b >> 6) & 3) * 256;             // 4 d-tiles
    int e  = b >> 8;                           // 8 experts
    int t  = threadIdx.x;
    const float* we = ew + (size_t)e * D_MODEL * D_FF + (size_t)d0 * D_FF + f0;
    int fg = (t & 15) * 4;                     // f-offset 0..60
    int dg = (t >> 4) * 16;                    // d-offset 0..240
    unsigned short v[4][16];
#pragma unroll
    for (int j = 0; j < 16; ++j) {
        float4 r = *(const float4*)(we + (size_t)(dg + j) * D_FF + fg);
        v[0][j] = f2bf(r.x); v[1][j] = f2bf(r.y);
        v[2][j] = f2bf(r.z); v[3][j] = f2bf(r.w);
    }
#pragma unroll
    for (int i = 0; i < 4; ++i) {
#pragma unroll
        for (int p = 0; p < 4; ++p) {
            union { unsigned short us[4]; uint2 u; } pk;
            pk.us[0] = v[i][p*4+0]; pk.us[1] = v[i][p*4+1];
            pk.us[2] = v[i][p*4+2]; pk.us[3] = v[i][p*4+3];
            *(uint2*)&tt[(size_t)(fg + i) * WST2 + dg + p * 4] = pk.u;
        }
    }
    __syncthreads();
    unsigned short* wte = wt + (size_t)e * D_FF * D_MODEL + (size_t)f0 * D_MODEL + d0;
    int fr = t >> 5;                           // 0..7
    int cr = (t & 31) * 8;                     // d-chunk 0..248
#pragma unroll
    for (int p = 0; p < 8; ++p) {
        int f = fr + p * 8;
        uint2 a = *(const uint2*)&tt[(size_t)f * WST2 + cr];
        uint2 c = *(const uint2*)&tt[(size_t)f * WST2 + cr + 4];
        uint4 o; o.x = a.x; o.y = a.y; o.z = c.x; o.w = c.y;
        *(uint4*)(wte + (size_t)f * D_MODEL + cr) = o;
    }
}

// -------- route: single block, histogram + scan + order-preserving scatter --------
__global__ __launch_bounds__(1024) void route_kernel(
    const int* __restrict__ top1, int* __restrict__ tile_expert, int* __restrict__ list)
{
    __shared__ int wtot[16][N_EXPERTS];
    __shared__ int wbase[16][N_EXPERTS];
    __shared__ int pofs[N_EXPERTS];
    int t = threadIdx.x, wv = t >> 6, l = t & 63;

    for (int i = t; i < MT_MAX * BM; i += 1024) list[i] = -1;

    int e8[8];
    const int4* tp = (const int4*)(top1 + t * 8);
    int4 a = tp[0], b = tp[1];
    e8[0] = a.x; e8[1] = a.y; e8[2] = a.z; e8[3] = a.w;
    e8[4] = b.x; e8[5] = b.y; e8[6] = b.z; e8[7] = b.w;
    int c[N_EXPERTS], s[N_EXPERTS];
#pragma unroll
    for (int e = 0; e < N_EXPERTS; ++e) c[e] = 0;
#pragma unroll
    for (int j = 0; j < 8; ++j) c[e8[j]]++;
#pragma unroll
    for (int e = 0; e < N_EXPERTS; ++e) s[e] = c[e];
    for (int off = 1; off < 64; off <<= 1) {
#pragma unroll
        for (int e = 0; e < N_EXPERTS; ++e) {
            int v = __shfl_up(s[e], off);
            if (l >= off) s[e] += v;
        }
    }
    if (l == 63)
#pragma unroll
        for (int e = 0; e < N_EXPERTS; ++e) wtot[wv][e] = s[e];
    __syncthreads();
    if (t == 0) {
        int cnt[N_EXPERTS];
        for (int e = 0; e < N_EXPERTS; ++e) {
            cnt[e] = 0;
            for (int w = 0; w < 16; ++w) { wbase[w][e] = cnt[e]; cnt[e] += wtot[w][e]; }
        }
        int off = 0;
        for (int e = 0; e < N_EXPERTS; ++e) {
            pofs[e] = off;
            int ntl = (cnt[e] + BM - 1) / BM;
            for (int k = 0; k < ntl; ++k) tile_expert[off / BM + k] = e;
            off += ntl * BM;
        }
        for (int k = off / BM; k < MT_MAX; ++k) tile_expert[k] = -1;
    }
    __syncthreads();
    int base[N_EXPERTS];
#pragma unroll
    for (int e = 0; e < N_EXPERTS; ++e) base[e] = pofs[e] + wbase[wv][e] + s[e] - c[e];
#pragma unroll
    for (int j = 0; j < 8; ++j) {
        int e = e8[j];
        list[base[e]++] = t * 8 + j;
    }
}

// -------- grouped GEMM (R4 exact): BK=64, double buffer, vmcnt(8) pipeline --------
__global__ __launch_bounds__(256) void gemm_kernel(
    const unsigned short* __restrict__ xb,   // [N][D] bf16
    const unsigned short* __restrict__ wt,   // [E][F][D] bf16
    const float* __restrict__ eb,            // [E][F]
    const int* __restrict__ tile_expert,
    const int* __restrict__ list,
    float* __restrict__ out)                 // [N][F]
{
    int bid = blockIdx.x;
    int xcd = bid & 7, w = bid >> 3;
    int mt  = w >> 2;
    int nt  = (xcd << 2) | (w & 3);
    int e = tile_expert[mt];
    if (e < 0) return;
    int n0 = nt * BN;

    __shared__ unsigned short As[2][BM * BK];   // 2 x 16 KB
    __shared__ unsigned short Bs[2][BN * BK];   // 2 x 16 KB
    __shared__ int toks[BM];

    int tid = threadIdx.x;
    int lane = tid & 63, wave = tid >> 6;
    if (tid < BM) toks[tid] = list[mt * BM + tid];
    __syncthreads();

    const unsigned short* gA[4];
    const unsigned short* gB[4];
    const unsigned short* wbase = wt + (size_t)e * D_FF * D_MODEL;
#pragma unroll
    for (int i = 0; i < 4; ++i) {
        int s = wave * 256 + i * 64 + lane;
        int row = s >> 3, c8 = (s & 7) ^ (row & 7);
        int ta = toks[row]; if (ta < 0) ta = 0;
        gA[i] = xb + (size_t)ta * D_MODEL + c8 * 8;
        gB[i] = wbase + (size_t)(n0 + row) * D_MODEL + c8 * 8;
    }

    auto stage = [&](int b, int kt) {
        int k0 = kt * BK;
        unsigned short* ap = &As[b][0];
        unsigned short* bp = &Bs[b][0];
#pragma unroll
        for (int i = 0; i < 4; ++i) GLDS(gA[i] + k0, ap + (size_t)(wave * 256 + i * 64) * 8);
#pragma unroll
        for (int i = 0; i < 4; ++i) GLDS(gB[i] + k0, bp + (size_t)(wave * 256 + i * 64) * 8);
    };

    floatx4 acc[4][4];
#pragma unroll
    for (int mi = 0; mi < 4; ++mi)
#pragma unroll
        for (int ni = 0; ni < 4; ++ni)
            acc[mi][ni] = (floatx4){0.f, 0.f, 0.f, 0.f};

    int mw = (wave >> 1) * 64;
    int nw = (wave & 1) * 64;
    int q = lane >> 4, r = lane & 15;
    int xr = r & 7;
    int ra[4], rb[4];
#pragma unroll
    for (int i = 0; i < 4; ++i) { ra[i] = (mw + i * 16 + r) * 8; rb[i] = (nw + i * 16 + r) * 8; }

    // prologue: tiles 0 and 1 in flight; wait for tile 0 only (vmcnt(8)).
    stage(0, 0);
    stage(1, 1);
    asm volatile("s_waitcnt vmcnt(8)" ::: "memory");
    __builtin_amdgcn_s_barrier();
    __builtin_amdgcn_sched_barrier(0);

    for (int kt = 0; kt < NKT; ++kt) {
        int cur = kt & 1;
        const unsigned short* Ac = &As[cur][0];
        const unsigned short* Bc = &Bs[cur][0];
#pragma unroll
        for (int ks = 0; ks < 2; ++ks) {
            int cq = (ks * 4 + q) ^ xr;
            short8 af[4], bf[4];
#pragma unroll
            for (int mi = 0; mi < 4; ++mi)
                af[mi] = *(const short8*)&Ac[(size_t)(ra[mi] + cq) * 8];
#pragma unroll
            for (int ni = 0; ni < 4; ++ni)
                bf[ni] = *(const short8*)&Bc[(size_t)(rb[ni] + cq) * 8];
#pragma unroll
            for (int mi = 0; mi < 4; ++mi)
#pragma unroll
                for (int ni = 0; ni < 4; ++ni)
                    acc[mi][ni] = __builtin_amdgcn_mfma_f32_16x16x32_bf16(
                        af[mi], bf[ni], acc[mi][ni], 0, 0, 0);
        }
        __builtin_amdgcn_sched_barrier(0);
        __builtin_amdgcn_s_barrier();           // all waves done reading buf[cur]
        if (kt + 2 < NKT) {
            stage(cur, kt + 2);                 // refill the buffer just consumed
            asm volatile("s_waitcnt vmcnt(8)" ::: "memory"); // tile kt+1 landed
        } else {
            asm volatile("s_waitcnt vmcnt(0)" ::: "memory");
        }
        __builtin_amdgcn_s_barrier();           // tile kt+1 visible to all waves
        __builtin_amdgcn_sched_barrier(0);
    }

    // epilogue: C/D layout col=lane&15, row=(lane>>4)*4+i  [m89-verified]
#pragma unroll
    for (int ni = 0; ni < 4; ++ni) {
        int f = n0 + nw + ni * 16 + r;
        float bias = eb[(size_t)e * D_FF + f];
#pragma unroll
        for (int mi = 0; mi < 4; ++mi) {
            int mbase = mw + mi * 16 + q * 4;
#pragma unroll
            for (int i = 0; i < 4; ++i) {
                int tok = toks[mbase + i];
                if (tok >= 0) out[(size_t)tok * D_FF + f] = acc[mi][ni][i] + bias;
            }
        }
    }
}

extern "C" void kernel_launch(void* const* d_in, const int* in_sizes, int n_in,
                              void* d_out, int out_size, void* d_ws, size_t ws_size,
                              hipStream_t stream) {
    const float* x  = (const float*)d_in[0];
    const float* gw = (const float*)d_in[1];
    const float* gb = (const float*)d_in[2];
    const float* ew = (const float*)d_in[3];
    const float* eb = (const float*)d_in[4];
    float* out = (float*)d_out;

    char* ws = (char*)d_ws;
    int* top1        = (int*)ws;                    // 32 KB
    int* tile_expert = (int*)(ws + 32768);          // 288 B
    int* list        = (int*)(ws + 36864);          // 72*128*4 = 36864 B
    unsigned short* xb = (unsigned short*)(ws + 131072);                          // 16.8 MB
    unsigned short* wt = (unsigned short*)(ws + 131072 + (size_t)N_TOKENS * D_MODEL * 2); // 67 MB

    hipLaunchKernelGGL(gate_kernel, dim3(GATE_BLOCKS), dim3(256), 0, stream,
                       x, gw, gb, xb, top1);
    hipLaunchKernelGGL(wconv_kernel, dim3(WCONV_BLOCKS), dim3(256), 0, stream,
                       ew, wt);
    hipLaunchKernelGGL(route_kernel, dim3(1), dim3(1024), 0, stream,
                       top1, tile_expert, list);
    hipLaunchKernelGGL(gemm_kernel, dim3(MT_MAX * NTILES), dim3(256), 0, stream,
                       xb, wt, eb, tile_expert, list, out);
}

// Round 4
// 422.973 us; speedup vs baseline: 1.0515x; 1.0419x over previous
//
#include <hip/hip_runtime.h>

// MoE top-1 layer, MI355X. N=8192 tokens, D=1024, F=4096, E=8.
// R7: gemm -> BK=32, TRIPLE-buffered (48.5 KB LDS -> 3 blocks/CU, 3 waves/SIMD),
//   stage-ahead-3 with counted vmcnt(8) (2 tiles always in flight).
//   Staged bytes unchanged vs R4 -- this round discriminates latency-bound
//   (expect ~-30%) vs VMEM-delivery-ceiling (expect flat).
//   Swizzle for 64B rows: c8 = (s&3) ^ (row&3) ^ ((row>>2)&3).
// gate/wconv/route unchanged from R6.

#define N_TOKENS 8192
#define D_MODEL  1024
#define D_FF     4096
#define N_EXPERTS 8

#define BM 128
#define BN 128
#define BK 32
#define NKT (D_MODEL / BK)                   // 32 k-iterations
#define NBUF 3
#define MT_MAX (N_TOKENS / BM + N_EXPERTS)   // 72 m-tiles worst case
#define NTILES (D_FF / BN)                   // 32 n-tiles
#define GATE_BLOCKS (N_TOKENS / 4)           // 2048
#define WCONV_BLOCKS ((D_FF / 64) * (D_MODEL / 256) * N_EXPERTS)  // 2048

typedef float  floatx4 __attribute__((ext_vector_type(4)));
typedef short  short8  __attribute__((ext_vector_type(8)));

__device__ __forceinline__ unsigned short f2bf(float f) {
    union { float f; unsigned u; } a; a.f = f;
    return (unsigned short)((a.u + 0x7fffu + ((a.u >> 16) & 1u)) >> 16); // RNE
}

#define GLDS(gp, lp) __builtin_amdgcn_global_load_lds( \
    (const __attribute__((address_space(1))) unsigned int*)(const void*)(gp), \
    (__attribute__((address_space(3))) unsigned int*)(void*)(lp), 16, 0, 0)

// -------- gate: fp32 gemv -> top1, + x -> xb bf16 --------
__global__ __launch_bounds__(256) void gate_kernel(
    const float* __restrict__ x, const float* __restrict__ gw,
    const float* __restrict__ gb,
    unsigned short* __restrict__ xb, int* __restrict__ top1)
{
    int wave = threadIdx.x >> 6;
    int l    = threadIdx.x & 63;
    int n = blockIdx.x * 4 + wave;
    const float4* xr = (const float4*)(x + (size_t)n * D_MODEL);
    float acc[N_EXPERTS];
#pragma unroll
    for (int e = 0; e < N_EXPERTS; ++e) acc[e] = 0.f;
#pragma unroll
    for (int j = 0; j < 4; ++j) {
        int d4 = j * 64 + l;
        float4 v = xr[d4];
        float vv[4] = { v.x, v.y, v.z, v.w };
#pragma unroll
        for (int t = 0; t < 4; ++t) {
            const float4* g = (const float4*)(gw + (size_t)(d4 * 4 + t) * N_EXPERTS);
            float4 g0 = g[0], g1 = g[1];
            acc[0] += vv[t] * g0.x; acc[1] += vv[t] * g0.y;
            acc[2] += vv[t] * g0.z; acc[3] += vv[t] * g0.w;
            acc[4] += vv[t] * g1.x; acc[5] += vv[t] * g1.y;
            acc[6] += vv[t] * g1.z; acc[7] += vv[t] * g1.w;
        }
        union { unsigned short us[4]; uint2 u; } pk;
        pk.us[0] = f2bf(v.x); pk.us[1] = f2bf(v.y);
        pk.us[2] = f2bf(v.z); pk.us[3] = f2bf(v.w);
        ((uint2*)(xb + (size_t)n * D_MODEL))[d4] = pk.u;
    }
#pragma unroll
    for (int e = 0; e < N_EXPERTS; ++e)
        for (int off = 32; off > 0; off >>= 1)
            acc[e] += __shfl_down(acc[e], off);
    if (l == 0) {
        float best = acc[0] + gb[0]; int be = 0;
#pragma unroll
        for (int e = 1; e < N_EXPERTS; ++e) {
            float v = acc[e] + gb[e];
            if (v > best) { best = v; be = e; }
        }
        top1[n] = be;
    }
}

// -------- wconv: ew f32 [E][D][F] -> wt bf16 [E][F][D], 64f x 256d tiles --------
#define WST2 260
__global__ __launch_bounds__(256) void wconv_kernel(
    const float* __restrict__ ew, unsigned short* __restrict__ wt)
{
    __shared__ unsigned short tt[64 * WST2];   // 33.3 KB
    int b  = blockIdx.x;
    int f0 = (b & 63) * 64;                    // 64 f-tiles
    int d0 = ((b >> 6) & 3) * 256;             // 4 d-tiles
    int e  = b >> 8;                           // 8 experts
    int t  = threadIdx.x;
    const float* we = ew + (size_t)e * D_MODEL * D_FF + (size_t)d0 * D_FF + f0;
    int fg = (t & 15) * 4;                     // f-offset 0..60
    int dg = (t >> 4) * 16;                    // d-offset 0..240
    unsigned short v[4][16];
#pragma unroll
    for (int j = 0; j < 16; ++j) {
        float4 r = *(const float4*)(we + (size_t)(dg + j) * D_FF + fg);
        v[0][j] = f2bf(r.x); v[1][j] = f2bf(r.y);
        v[2][j] = f2bf(r.z); v[3][j] = f2bf(r.w);
    }
#pragma unroll
    for (int i = 0; i < 4; ++i) {
#pragma unroll
        for (int p = 0; p < 4; ++p) {
            union { unsigned short us[4]; uint2 u; } pk;
            pk.us[0] = v[i][p*4+0]; pk.us[1] = v[i][p*4+1];
            pk.us[2] = v[i][p*4+2]; pk.us[3] = v[i][p*4+3];
            *(uint2*)&tt[(size_t)(fg + i) * WST2 + dg + p * 4] = pk.u;
        }
    }
    __syncthreads();
    unsigned short* wte = wt + (size_t)e * D_FF * D_MODEL + (size_t)f0 * D_MODEL + d0;
    int fr = t >> 5;                           // 0..7
    int cr = (t & 31) * 8;                     // d-chunk 0..248
#pragma unroll
    for (int p = 0; p < 8; ++p) {
        int f = fr + p * 8;
        uint2 a = *(const uint2*)&tt[(size_t)f * WST2 + cr];
        uint2 c = *(const uint2*)&tt[(size_t)f * WST2 + cr + 4];
        uint4 o; o.x = a.x; o.y = a.y; o.z = c.x; o.w = c.y;
        *(uint4*)(wte + (size_t)f * D_MODEL + cr) = o;
    }
}

// -------- route: single block, histogram + scan + order-preserving scatter --------
__global__ __launch_bounds__(1024) void route_kernel(
    const int* __restrict__ top1, int* __restrict__ tile_expert, int* __restrict__ list)
{
    __shared__ int wtot[16][N_EXPERTS];
    __shared__ int wbase[16][N_EXPERTS];
    __shared__ int pofs[N_EXPERTS];
    int t = threadIdx.x, wv = t >> 6, l = t & 63;

    for (int i = t; i < MT_MAX * BM; i += 1024) list[i] = -1;

    int e8[8];
    const int4* tp = (const int4*)(top1 + t * 8);
    int4 a = tp[0], b = tp[1];
    e8[0] = a.x; e8[1] = a.y; e8[2] = a.z; e8[3] = a.w;
    e8[4] = b.x; e8[5] = b.y; e8[6] = b.z; e8[7] = b.w;
    int c[N_EXPERTS], s[N_EXPERTS];
#pragma unroll
    for (int e = 0; e < N_EXPERTS; ++e) c[e] = 0;
#pragma unroll
    for (int j = 0; j < 8; ++j) c[e8[j]]++;
#pragma unroll
    for (int e = 0; e < N_EXPERTS; ++e) s[e] = c[e];
    for (int off = 1; off < 64; off <<= 1) {
#pragma unroll
        for (int e = 0; e < N_EXPERTS; ++e) {
            int v = __shfl_up(s[e], off);
            if (l >= off) s[e] += v;
        }
    }
    if (l == 63)
#pragma unroll
        for (int e = 0; e < N_EXPERTS; ++e) wtot[wv][e] = s[e];
    __syncthreads();
    if (t == 0) {
        int cnt[N_EXPERTS];
        for (int e = 0; e < N_EXPERTS; ++e) {
            cnt[e] = 0;
            for (int w = 0; w < 16; ++w) { wbase[w][e] = cnt[e]; cnt[e] += wtot[w][e]; }
        }
        int off = 0;
        for (int e = 0; e < N_EXPERTS; ++e) {
            pofs[e] = off;
            int ntl = (cnt[e] + BM - 1) / BM;
            for (int k = 0; k < ntl; ++k) tile_expert[off / BM + k] = e;
            off += ntl * BM;
        }
        for (int k = off / BM; k < MT_MAX; ++k) tile_expert[k] = -1;
    }
    __syncthreads();
    int base[N_EXPERTS];
#pragma unroll
    for (int e = 0; e < N_EXPERTS; ++e) base[e] = pofs[e] + wbase[wv][e] + s[e] - c[e];
#pragma unroll
    for (int j = 0; j < 8; ++j) {
        int e = e8[j];
        list[base[e]++] = t * 8 + j;
    }
}

// -------- grouped GEMM: BK=32, TRIPLE buffer, vmcnt(8) stage-ahead-3 --------
__global__ __launch_bounds__(256, 3) void gemm_kernel(
    const unsigned short* __restrict__ xb,   // [N][D] bf16
    const unsigned short* __restrict__ wt,   // [E][F][D] bf16
    const float* __restrict__ eb,            // [E][F]
    const int* __restrict__ tile_expert,
    const int* __restrict__ list,
    float* __restrict__ out)                 // [N][F]
{
    int bid = blockIdx.x;
    int xcd = bid & 7, w = bid >> 3;
    int mt  = w >> 2;
    int nt  = (xcd << 2) | (w & 3);
    int e = tile_expert[mt];
    if (e < 0) return;
    int n0 = nt * BN;

    __shared__ unsigned short As[NBUF][BM * BK];   // 3 x 8 KB
    __shared__ unsigned short Bs[NBUF][BN * BK];   // 3 x 8 KB
    __shared__ int toks[BM];

    int tid = threadIdx.x;
    int lane = tid & 63, wave = tid >> 6;
    if (tid < BM) toks[tid] = list[mt * BM + tid];
    __syncthreads();

    // staging: 512 16B-chunks per operand per K-tile; 2 GLDS/wave each.
    // LDS slot s holds logical chunk (row = s>>2, c8 = (s&3)^(row&3)^((row>>2)&3)).
    const unsigned short* gA[2];
    const unsigned short* gB[2];
    const unsigned short* wbase = wt + (size_t)e * D_FF * D_MODEL;
#pragma unroll
    for (int i = 0; i < 2; ++i) {
        int s = wave * 128 + i * 64 + lane;     // 0..511
        int row = s >> 2;
        int c8 = (s & 3) ^ (row & 3) ^ ((row >> 2) & 3);
        int ta = toks[row]; if (ta < 0) ta = 0;
        gA[i] = xb + (size_t)ta * D_MODEL + c8 * 8;
        gB[i] = wbase + (size_t)(n0 + row) * D_MODEL + c8 * 8;
    }

    // 4 GLDS per wave per stage (2 A + 2 B).
    auto stage = [&](int b, int kt) {
        int k0 = kt * BK;
        unsigned short* ap = &As[b][0];
        unsigned short* bp = &Bs[b][0];
#pragma unroll
        for (int i = 0; i < 2; ++i) GLDS(gA[i] + k0, ap + (size_t)(wave * 128 + i * 64) * 8);
#pragma unroll
        for (int i = 0; i < 2; ++i) GLDS(gB[i] + k0, bp + (size_t)(wave * 128 + i * 64) * 8);
    };

    floatx4 acc[4][4];
#pragma unroll
    for (int mi = 0; mi < 4; ++mi)
#pragma unroll
        for (int ni = 0; ni < 4; ++ni)
            acc[mi][ni] = (floatx4){0.f, 0.f, 0.f, 0.f};

    int mw = (wave >> 1) * 64;
    int nw = (wave & 1) * 64;
    int q = lane >> 4, r = lane & 15;
    // read addresses (element offsets), swizzle folded in at compile of mi/ni:
    int pa[4], pb[4];
#pragma unroll
    for (int i = 0; i < 4; ++i) {
        int rowA = mw + i * 16 + r;
        pa[i] = rowA * BK + ((q ^ (rowA & 3) ^ ((rowA >> 2) & 3)) * 8);
        int rowB = nw + i * 16 + r;
        pb[i] = rowB * BK + ((q ^ (rowB & 3) ^ ((rowB >> 2) & 3)) * 8);
    }

    // prologue: tiles 0,1,2 in flight; wait for tile 0 only (vmcnt(8)).
    stage(0, 0);
    stage(1, 1);
    stage(2, 2);
    asm volatile("s_waitcnt vmcnt(8)" ::: "memory");
    __builtin_amdgcn_s_barrier();
    __builtin_amdgcn_sched_barrier(0);

    int cur = 0;
    for (int kt = 0; kt < NKT; ++kt) {
        const unsigned short* Ac = &As[cur][0];
        const unsigned short* Bc = &Bs[cur][0];
        short8 af[4], bf[4];
#pragma unroll
        for (int mi = 0; mi < 4; ++mi)
            af[mi] = *(const short8*)&Ac[pa[mi]];
#pragma unroll
        for (int ni = 0; ni < 4; ++ni)
            bf[ni] = *(const short8*)&Bc[pb[ni]];
#pragma unroll
        for (int mi = 0; mi < 4; ++mi)
#pragma unroll
            for (int ni = 0; ni < 4; ++ni)
                acc[mi][ni] = __builtin_amdgcn_mfma_f32_16x16x32_bf16(
                    af[mi], bf[ni], acc[mi][ni], 0, 0, 0);
        __builtin_amdgcn_sched_barrier(0);
        __builtin_amdgcn_s_barrier();           // all waves done reading buf[cur]
        if (kt + 3 < NKT) {
            stage(cur, kt + 3);                 // refill the buffer just consumed
            // outstanding = tiles kt+2, kt+3 (8 loads); wait tile kt+1 landed
            asm volatile("s_waitcnt vmcnt(8)" ::: "memory");
        } else if (kt == NKT - 3) {
            asm volatile("s_waitcnt vmcnt(4)" ::: "memory"); // tile kt+1 landed
        } else if (kt == NKT - 2) {
            asm volatile("s_waitcnt vmcnt(0)" ::: "memory"); // last tile landed
        }
        __builtin_amdgcn_s_barrier();           // tile kt+1 visible to all waves
        __builtin_amdgcn_sched_barrier(0);
        cur = (cur == NBUF - 1) ? 0 : cur + 1;
    }

    // epilogue: C/D layout col=lane&15, row=(lane>>4)*4+i  [m89-verified]
#pragma unroll
    for (int ni = 0; ni < 4; ++ni) {
        int f = n0 + nw + ni * 16 + r;
        float bias = eb[(size_t)e * D_FF + f];
#pragma unroll
        for (int mi = 0; mi < 4; ++mi) {
            int mbase = mw + mi * 16 + q * 4;
#pragma unroll
            for (int i = 0; i < 4; ++i) {
                int tok = toks[mbase + i];
                if (tok >= 0) out[(size_t)tok * D_FF + f] = acc[mi][ni][i] + bias;
            }
        }
    }
}

extern "C" void kernel_launch(void* const* d_in, const int* in_sizes, int n_in,
                              void* d_out, int out_size, void* d_ws, size_t ws_size,
                              hipStream_t stream) {
    const float* x  = (const float*)d_in[0];
    const float* gw = (const float*)d_in[1];
    const float* gb = (const float*)d_in[2];
    const float* ew = (const float*)d_in[3];
    const float* eb = (const float*)d_in[4];
    float* out = (float*)d_out;

    char* ws = (char*)d_ws;
    int* top1        = (int*)ws;                    // 32 KB
    int* tile_expert = (int*)(ws + 32768);          // 288 B
    int* list        = (int*)(ws + 36864);          // 72*128*4 = 36864 B
    unsigned short* xb = (unsigned short*)(ws + 131072);                          // 16.8 MB
    unsigned short* wt = (unsigned short*)(ws + 131072 + (size_t)N_TOKENS * D_MODEL * 2); // 67 MB

    hipLaunchKernelGGL(gate_kernel, dim3(GATE_BLOCKS), dim3(256), 0, stream,
                       x, gw, gb, xb, top1);
    hipLaunchKernelGGL(wconv_kernel, dim3(WCONV_BLOCKS), dim3(256), 0, stream,
                       ew, wt);
    hipLaunchKernelGGL(route_kernel, dim3(1), dim3(1024), 0, stream,
                       top1, tile_expert, list);
    hipLaunchKernelGGL(gemm_kernel, dim3(MT_MAX * NTILES), dim3(256), 0, stream,
                       xb, wt, eb, tile_expert, list, out);
}